// Round 1
// baseline (57.092 us; speedup 1.0000x reference)
//
#include <hip/hip_runtime.h>
#include <hip/hip_bf16.h>

// Pre-kernel: single block. alpha = mean(|w|) over 4096 elems; wq = alpha * ternary(w).
__global__ __launch_bounds__(256) void ternary_quant_kernel(
    const float* __restrict__ w, float* __restrict__ wq, int n) {
    __shared__ float red[256];
    __shared__ float alpha_s;
    const int tid = threadIdx.x;
    float s = 0.f;
    for (int i = tid; i < n; i += 256) s += fabsf(w[i]);
    red[tid] = s;
    __syncthreads();
    for (int off = 128; off > 0; off >>= 1) {
        if (tid < off) red[tid] += red[tid + off];
        __syncthreads();
    }
    if (tid == 0) alpha_s = red[0] / (float)n;
    __syncthreads();
    const float alpha = alpha_s;
    const float thr = 0.7f * alpha;
    for (int i = tid; i < n; i += 256) {
        float v = w[i];
        float t = (fabsf(v) < thr) ? 0.f : (v > 0.f ? 1.f : (v < 0.f ? -1.f : 0.f));
        wq[i] = alpha * t;
    }
}

// Main conv: one thread per filter f (256/block), 64 output positions per block.
// y[b,l,f] = bias[f] + sum_k wq[k,f] * x[b, l+k-7]   (SAME pad: lo=7, hi=8)
__global__ __launch_bounds__(256) void ternary_conv1d_kernel(
    const float* __restrict__ x,   // (B, L)
    const float* __restrict__ wq,  // (16, 256)
    const float* __restrict__ bias,// (256)
    float* __restrict__ y,         // (B, L, 256)
    int L, int ltiles) {
    const int f = threadIdx.x;                  // 0..255
    const int bid = blockIdx.x;
    const int lt = bid % ltiles;
    const int b  = bid / ltiles;
    const int l0 = lt * 64;

    __shared__ float xs[80];                    // 79 used: x[l0-7 .. l0+71]
    if (f < 79) {
        int gl = l0 - 7 + f;
        xs[f] = (gl >= 0 && gl < L) ? x[(size_t)b * L + gl] : 0.f;
    }

    float wqr[16];
#pragma unroll
    for (int k = 0; k < 16; ++k) wqr[k] = wq[k * 256 + f];
    const float bf = bias[f];

    __syncthreads();

    float* out = y + ((size_t)b * L + l0) * 256 + f;
#pragma unroll
    for (int c = 0; c < 4; ++c) {
        float xv[31];
#pragma unroll
        for (int i = 0; i < 31; ++i) xv[i] = xs[c * 16 + i];
#pragma unroll
        for (int l = 0; l < 16; ++l) {
            float acc = bf;
#pragma unroll
            for (int k = 0; k < 16; ++k) acc = fmaf(wqr[k], xv[l + k], acc);
            out[(size_t)(c * 16 + l) * 256] = acc;
        }
    }
}

extern "C" void kernel_launch(void* const* d_in, const int* in_sizes, int n_in,
                              void* d_out, int out_size, void* d_ws, size_t ws_size,
                              hipStream_t stream) {
    const float* x = (const float*)d_in[0];   // (32, 8192, 1)
    const float* w = (const float*)d_in[1];   // (16, 1, 256)
    const float* b = (const float*)d_in[2];   // (256,)
    float* y = (float*)d_out;                 // (32, 8192, 256)
    float* wq = (float*)d_ws;                 // 4096 floats scratch

    const int B = 32;
    const int L = in_sizes[0] / B;            // 8192
    const int nW = in_sizes[1];               // 4096
    const int ltiles = L / 64;                // 128

    ternary_quant_kernel<<<1, 256, 0, stream>>>(w, wq, nW);
    ternary_conv1d_kernel<<<B * ltiles, 256, 0, stream>>>(x, wq, b, y, L, ltiles);
}